// Round 3
// baseline (190.308 us; speedup 1.0000x reference)
//
#include <hip/hip_runtime.h>
#include <cmath>

// SSIM loss, row-sliding fused kernel, merged 3D+2D dispatch.
// Block = 512 threads = one full image row (1 thread/column), BAND=32 rows.
// Per row-step: coalesced global load -> double-buffered LDS row buffer ->
// horizontal 11-tap blur of 5 channels (a,b,a2,b2,ab) -> vertical blur via
// rotating 11-slot register accumulators -> SSIM (single rcp) -> block
// reduce -> one double atomicAdd per block.
// Depth-mean of img2 precomputed by a float4 BW-bound kernel into d_ws.

#define WSZ 11
#define IMG 512
#define SLICE (IMG * IMG)
#define BAND 32
#define BANDS (IMG / BAND)        // 16
#define STEPS (((BAND + 20) / 11) * 11)   // 44 >= BAND+10

struct G11 { float w[WSZ]; };

__global__ __launch_bounds__(512, 4)
void ssim_merged_kernel(const float* __restrict__ A3, const float* __restrict__ B3,
                        const float* __restrict__ A2, const float* __restrict__ B2,
                        double* __restrict__ acc, G11 gw, int units2d)
{
    __shared__ float rbA[2][528];   // row buffers, 5-wide zero pad each side
    __shared__ float rbB[2][528];
    __shared__ float bsum[8];

    const int x = threadIdx.x;      // column 0..511

    // decode work unit: [0, units2d) = 2D pairs, rest = 3D slice pairs.
    const int unit = blockIdx.x;
    const float* Ap;
    const float* Bp;
    double* accp;
    int y0;
    if (unit < units2d) {
        int img  = unit >> 4;           // /BANDS
        int band = unit & (BANDS - 1);
        Ap = A2 + (long)img * SLICE;
        Bp = B2 + (long)img * SLICE;
        accp = acc + 1;
        y0 = band * BAND;
    } else {
        int u = unit - units2d;
        int slice = u >> 4;
        int band  = u & (BANDS - 1);
        Ap = A3 + (long)slice * SLICE;
        Bp = B3 + (long)slice * SLICE;
        accp = acc + 0;
        y0 = band * BAND;
    }

    // zero the horizontal pads once
    if (x < 5) {
        rbA[0][x] = 0.f; rbA[1][x] = 0.f;
        rbB[0][x] = 0.f; rbB[1][x] = 0.f;
        rbA[0][517 + x] = 0.f; rbA[1][517 + x] = 0.f;
        rbB[0][517 + x] = 0.f; rbB[1][517 + x] = 0.f;
    }

    // rotating vertical accumulators, 11 slots x 5 channels, static-indexed
    float aM1[11], aM2[11], aXX[11], aYY[11], aZZ[11];
    #pragma unroll
    for (int i = 0; i < 11; i++) {
        aM1[i] = 0.f; aM2[i] = 0.f; aXX[i] = 0.f; aYY[i] = 0.f; aZZ[i] = 0.f;
    }

    float sum = 0.f;

    // prefetch row for t=0 (r = y0-5)
    float aN = 0.f, bN = 0.f;
    {
        int r = y0 - 5;
        if (r >= 0 && r < IMG) {
            aN = Ap[(long)r * IMG + x];
            bN = Bp[(long)r * IMG + x];
        }
    }
    __syncthreads();   // pads visible before first tap reads

    for (int t0 = 0; t0 < STEPS; t0 += 11) {
        #pragma unroll
        for (int u = 0; u < 11; u++) {
            const int t = t0 + u;
            if (t < BAND + 10) {                        // skip dead pad steps
                const int r = y0 - 5 + t;               // input row this step
                const bool rv = (r >= 0) && (r < IMG);  // block-uniform
                const int buf = t & 1;

                float h1 = 0.f, h2 = 0.f, h3 = 0.f, h4 = 0.f, h5 = 0.f;

                if (rv) {
                    rbA[buf][x + 5] = aN;
                    rbB[buf][x + 5] = bN;
                }

                // prefetch next row while this row's LDS write drains
                {
                    int rn = r + 1;
                    aN = 0.f; bN = 0.f;
                    if ((t + 1 < BAND + 10) && rn >= 0 && rn < IMG) {
                        aN = Ap[(long)rn * IMG + x];
                        bN = Bp[(long)rn * IMG + x];
                    }
                }

                if (rv) {
                    __syncthreads();
                    #pragma unroll
                    for (int k = 0; k < WSZ; k++) {
                        float gk = gw.w[k];
                        float va = rbA[buf][x + k];
                        float vb = rbB[buf][x + k];
                        float ta = gk * va, tb = gk * vb;
                        h1 += ta;      h2 += tb;
                        h3 += ta * va; h4 += tb * vb; h5 += ta * vb;
                    }
                }

                // vertical accumulate: h contributes to outputs completing at
                // steps t..t+10 with weight g[10-j]
                #pragma unroll
                for (int j = 0; j < 11; j++) {
                    const int s = (u + j) % 11;          // compile-time
                    const float gj = gw.w[10 - j];
                    aM1[s] += gj * h1;
                    aM2[s] += gj * h2;
                    aXX[s] += gj * h3;
                    aYY[s] += gj * h4;
                    aZZ[s] += gj * h5;
                }

                // slot u completes output row o = y0 - 10 + t
                if (t >= 10) {
                    float m1 = aM1[u], m2 = aM2[u];
                    float xx = aXX[u], yy = aYY[u], zz = aZZ[u];
                    float m1s = m1 * m1, m2s = m2 * m2, m12 = m1 * m2;
                    float s1 = xx - m1s, s2 = yy - m2s, s12 = zz - m12;
                    const float C1 = 1e-4f, C2 = 9e-4f;
                    float d1 = m1s + m2s + C1;
                    float d2 = s1 + s2 + C2;
                    float d3 = __builtin_amdgcn_sqrtf(s1) * __builtin_amdgcn_sqrtf(s2) + C2;
                    float num = (2.f * m12 + C1) * (2.f * s12 + C2) * (s12 + C2);
                    sum += num * __builtin_amdgcn_rcpf(d1 * d2 * d3);
                }
                aM1[u] = 0.f; aM2[u] = 0.f; aXX[u] = 0.f; aYY[u] = 0.f; aZZ[u] = 0.f;
            }
        }
    }

    // block reduction: wave shuffle -> LDS -> one atomic per block
    for (int off = 32; off > 0; off >>= 1)
        sum += __shfl_down(sum, off, 64);
    if ((x & 63) == 0) bsum[x >> 6] = sum;
    __syncthreads();
    if (x == 0) {
        float tot = 0.f;
        #pragma unroll
        for (int w = 0; w < 8; w++) tot += bsum[w];
        atomicAdd(accp, (double)tot);
    }
}

// b2 = mean over 16 depth slices of img2, vectorized float4.
__global__ __launch_bounds__(256) void depth_mean4_kernel(
    const float4* __restrict__ img2, float4* __restrict__ b2)
{
    const int per = SLICE / 4;                       // 65536 float4 per slice
    int idx = blockIdx.x * 256 + threadIdx.x;        // 0 .. 4*per-1
    int b = idx >> 16;
    int p = idx & (per - 1);
    const float4* src = img2 + (long)b * 16 * per + p;
    float sx = 0.f, sy = 0.f, sz = 0.f, sw = 0.f;
    #pragma unroll
    for (int d = 0; d < 16; d++) {
        float4 v = src[(long)d * per];
        sx += v.x; sy += v.y; sz += v.z; sw += v.w;
    }
    float4 o; o.x = sx * 0.0625f; o.y = sy * 0.0625f; o.z = sz * 0.0625f; o.w = sw * 0.0625f;
    b2[idx] = o;
}

__global__ void finalize_kernel(const double* __restrict__ acc, float* __restrict__ out)
{
    double loss3 = 1.0 - acc[0] / (64.0 * (double)SLICE);
    double loss2 = 1.0 - acc[1] / (4.0 * (double)SLICE);
    out[0] = (float)(loss3 + loss2);
}

extern "C" void kernel_launch(void* const* d_in, const int* in_sizes, int n_in,
                              void* d_out, int out_size, void* d_ws, size_t ws_size,
                              hipStream_t stream)
{
    const float* img1_3d = (const float*)d_in[0];   // [4,1,16,512,512] -> 64 slices
    const float* img1_2d = (const float*)d_in[1];   // [4,1,512,512]
    const float* img2    = (const float*)d_in[2];   // [4,1,16,512,512]
    float* out = (float*)d_out;

    double* acc = (double*)d_ws;                    // [0]=3D sum, [1]=2D sum
    float*  b2  = (float*)((char*)d_ws + 256);      // 4 MB depth-mean buffer

    // Gaussian weights, computed like cv2.getGaussianKernel(11, 1.5) in double.
    G11 gw;
    {
        double g[WSZ], s = 0.0;
        for (int i = 0; i < WSZ; i++) {
            double xx = (double)i - (WSZ - 1) / 2.0;
            g[i] = std::exp(-(xx * xx) / (2.0 * 1.5 * 1.5));
            s += g[i];
        }
        for (int i = 0; i < WSZ; i++) gw.w[i] = (float)(g[i] / s);
    }

    hipMemsetAsync(acc, 0, 2 * sizeof(double), stream);

    // depth mean of img2 -> b2 (BW-bound, ~68 MB)
    depth_mean4_kernel<<<(4 * SLICE / 4) / 256, 256, 0, stream>>>(
        (const float4*)img2, (float4*)b2);

    // merged SSIM: units 0..63 = 2D (4 imgs x 16 bands), 64..1087 = 3D
    const int units2d = 4 * BANDS;                  // 64
    const int units3d = 64 * BANDS;                 // 1024
    ssim_merged_kernel<<<units2d + units3d, 512, 0, stream>>>(
        img1_3d, img2, img1_2d, b2, acc, gw, units2d);

    finalize_kernel<<<1, 1, 0, stream>>>(acc, out);
}

// Round 4
// 154.278 us; speedup vs baseline: 1.2335x; 1.2335x over previous
//
#include <hip/hip_runtime.h>
#include <cmath>

// SSIM loss, vertical-first row-sliding kernel, merged 3D+2D dispatch.
// Block = 512 threads = one image row (1 thread/column), BAND=32 output rows.
// Per step: coalesced load of one input row -> 11-row (a,b) register ring ->
// recompute 5 vertical Gaussian sums from ring -> one 5-channel row to LDS
// (float4 + float, double-buffered) -> barrier -> horizontal 11-tap blur +
// SSIM -> block reduce -> one double atomicAdd per block.
// Register footprint ~45 VGPR => 8 waves/SIMD at __launch_bounds__(512,4),
// no spills (round-3 lesson: 55 vertical accumulators spilled at the 64-cap).

#define WSZ 11
#define IMG 512
#define SLICE (IMG * IMG)
#define BAND 32
#define BANDS (IMG / BAND)      // 16
#define TSTEPS (BAND + 10)      // 42 row steps per band

struct G11 { float w[WSZ]; };

__global__ __launch_bounds__(512, 4)
void ssim_vfirst_kernel(const float* __restrict__ A3, const float* __restrict__ B3,
                        const float* __restrict__ A2, const float* __restrict__ B2,
                        double* __restrict__ acc, G11 gw, int units2d)
{
    __shared__ float4 vs4[2][528];   // (m1, m2, xx, yy) per column, 5-pad each side
    __shared__ float  vsz[2][528];   // zz channel
    __shared__ float  bsum[8];

    const int x = threadIdx.x;       // column 0..511

    // decode work unit: [0, units2d) = 2D pairs, rest = 3D slice pairs
    const int unit = blockIdx.x;
    const float* Ap;
    const float* Bp;
    double* accp;
    int y0;
    if (unit < units2d) {
        int img  = unit >> 4;        // / BANDS
        int band = unit & (BANDS - 1);
        Ap = A2 + (long)img * SLICE;
        Bp = B2 + (long)img * SLICE;
        accp = acc + 1;
        y0 = band * BAND;
    } else {
        int uu = unit - units2d;
        int slice = uu >> 4;
        int band  = uu & (BANDS - 1);
        Ap = A3 + (long)slice * SLICE;
        Bp = B3 + (long)slice * SLICE;
        accp = acc + 0;
        y0 = band * BAND;
    }

    // zero the horizontal pads once (cols 0..4 and 517..521)
    if (x < 5) {
        float4 z4 = make_float4(0.f, 0.f, 0.f, 0.f);
        vs4[0][x] = z4;        vs4[1][x] = z4;
        vs4[0][517 + x] = z4;  vs4[1][517 + x] = z4;
        vsz[0][x] = 0.f;       vsz[1][x] = 0.f;
        vsz[0][517 + x] = 0.f; vsz[1][517 + x] = 0.f;
    }

    // 11-row register ring of raw (a, b) — statically indexed via unroll-by-11
    float ra[11], rb[11];
    #pragma unroll
    for (int i = 0; i < 11; i++) { ra[i] = 0.f; rb[i] = 0.f; }

    float sum = 0.f;

    // prefetch first input row (r = y0 - 5)
    float aN = 0.f, bN = 0.f;
    {
        int r = y0 - 5;
        if (r >= 0 && r < IMG) {
            aN = Ap[(long)r * IMG + x];
            bN = Bp[(long)r * IMG + x];
        }
    }
    __syncthreads();   // pads visible before first horizontal reads

    for (int t0 = 0; t0 < 44; t0 += 11) {
        #pragma unroll
        for (int u = 0; u < 11; u++) {
            const int t = t0 + u;              // step index; t0 % 11 == 0
            if (t < TSTEPS) {                  // block-uniform
                // insert prefetched row into ring slot (t % 11 == u, static)
                ra[u] = aN;
                rb[u] = bN;

                // prefetch next row
                {
                    int rn = y0 - 4 + t;
                    aN = 0.f; bN = 0.f;
                    if ((t + 1 < TSTEPS) && rn >= 0 && rn < IMG) {
                        aN = Ap[(long)rn * IMG + x];
                        bN = Bp[(long)rn * IMG + x];
                    }
                }

                if (t >= 10) {                 // ring full: output row o = y0 + t - 10
                    // vertical sums: slot (u+1+j)%11 holds input row o-5+j
                    float m1 = 0.f, m2 = 0.f, xx = 0.f, yy = 0.f, zz = 0.f;
                    #pragma unroll
                    for (int j = 0; j < 11; j++) {
                        const int s = (u + 1 + j) % 11;   // compile-time
                        const float gj = gw.w[j];
                        float ga = gj * ra[s];
                        float gb = gj * rb[s];
                        m1 += ga;        m2 += gb;
                        xx += ga * ra[s];
                        yy += gb * rb[s];
                        zz += ga * rb[s];
                    }
                    const int buf = t & 1;
                    vs4[buf][x + 5] = make_float4(m1, m2, xx, yy);
                    vsz[buf][x + 5] = zz;
                    __syncthreads();

                    // horizontal 11-tap blur of the 5 channels
                    float M1 = 0.f, M2 = 0.f, XX = 0.f, YY = 0.f, ZZ = 0.f;
                    #pragma unroll
                    for (int k = 0; k < WSZ; k++) {
                        const float gk = gw.w[k];
                        float4 v = vs4[buf][x + k];
                        M1 += gk * v.x;
                        M2 += gk * v.y;
                        XX += gk * v.z;
                        YY += gk * v.w;
                        ZZ += gk * vsz[buf][x + k];
                    }

                    // SSIM formula (single rcp)
                    float m1s = M1 * M1, m2s = M2 * M2, m12 = M1 * M2;
                    float s1 = XX - m1s, s2 = YY - m2s, s12 = ZZ - m12;
                    const float C1 = 1e-4f, C2 = 9e-4f;
                    float d1 = m1s + m2s + C1;
                    float d2 = s1 + s2 + C2;
                    float d3 = __builtin_amdgcn_sqrtf(s1) * __builtin_amdgcn_sqrtf(s2) + C2;
                    float num = (2.f * m12 + C1) * (2.f * s12 + C2) * (s12 + C2);
                    sum += num * __builtin_amdgcn_rcpf(d1 * d2 * d3);
                }
            }
        }
    }

    // block reduction: wave shuffle -> LDS -> one atomic per block
    for (int off = 32; off > 0; off >>= 1)
        sum += __shfl_down(sum, off, 64);
    if ((x & 63) == 0) bsum[x >> 6] = sum;
    __syncthreads();
    if (x == 0) {
        float tot = 0.f;
        #pragma unroll
        for (int w = 0; w < 8; w++) tot += bsum[w];
        atomicAdd(accp, (double)tot);
    }
}

// b2 = mean over 16 depth slices of img2, vectorized float4 (BW-bound).
__global__ __launch_bounds__(256) void depth_mean4_kernel(
    const float4* __restrict__ img2, float4* __restrict__ b2)
{
    const int per = SLICE / 4;                       // 65536 float4 per slice
    int idx = blockIdx.x * 256 + threadIdx.x;        // 0 .. 4*per-1
    int b = idx >> 16;
    int p = idx & (per - 1);
    const float4* src = img2 + (long)b * 16 * per + p;
    float sx = 0.f, sy = 0.f, sz = 0.f, sw = 0.f;
    #pragma unroll
    for (int d = 0; d < 16; d++) {
        float4 v = src[(long)d * per];
        sx += v.x; sy += v.y; sz += v.z; sw += v.w;
    }
    float4 o; o.x = sx * 0.0625f; o.y = sy * 0.0625f; o.z = sz * 0.0625f; o.w = sw * 0.0625f;
    b2[idx] = o;
}

__global__ void finalize_kernel(const double* __restrict__ acc, float* __restrict__ out)
{
    double loss3 = 1.0 - acc[0] / (64.0 * (double)SLICE);
    double loss2 = 1.0 - acc[1] / (4.0 * (double)SLICE);
    out[0] = (float)(loss3 + loss2);
}

extern "C" void kernel_launch(void* const* d_in, const int* in_sizes, int n_in,
                              void* d_out, int out_size, void* d_ws, size_t ws_size,
                              hipStream_t stream)
{
    const float* img1_3d = (const float*)d_in[0];   // [4,1,16,512,512] -> 64 slices
    const float* img1_2d = (const float*)d_in[1];   // [4,1,512,512]
    const float* img2    = (const float*)d_in[2];   // [4,1,16,512,512]
    float* out = (float*)d_out;

    double* acc = (double*)d_ws;                    // [0]=3D sum, [1]=2D sum
    float*  b2  = (float*)((char*)d_ws + 256);      // 4 MB depth-mean buffer

    // Gaussian weights, like cv2.getGaussianKernel(11, 1.5) in double.
    G11 gw;
    {
        double g[WSZ], s = 0.0;
        for (int i = 0; i < WSZ; i++) {
            double xx = (double)i - (WSZ - 1) / 2.0;
            g[i] = std::exp(-(xx * xx) / (2.0 * 1.5 * 1.5));
            s += g[i];
        }
        for (int i = 0; i < WSZ; i++) gw.w[i] = (float)(g[i] / s);
    }

    hipMemsetAsync(acc, 0, 2 * sizeof(double), stream);

    // depth mean of img2 -> b2 (68 MB, ~12 us)
    depth_mean4_kernel<<<(4 * SLICE / 4) / 256, 256, 0, stream>>>(
        (const float4*)img2, (float4*)b2);

    // merged SSIM: units 0..63 = 2D (4 imgs x 16 bands), 64..1087 = 3D
    const int units2d = 4 * BANDS;                  // 64
    const int units3d = 64 * BANDS;                 // 1024
    ssim_vfirst_kernel<<<units2d + units3d, 512, 0, stream>>>(
        img1_3d, img2, img1_2d, b2, acc, gw, units2d);

    finalize_kernel<<<1, 1, 0, stream>>>(acc, out);
}